// Round 17
// baseline (370.525 us; speedup 1.0000x reference)
//
#include <hip/hip_runtime.h>
#include <math.h>
#include <limits.h>

#define NNODE 50000
#define NEDGE 800000
#define NFEAT 256
#define NHID  128
#define NTEST 5000
#define NTRAIN 5000
#define NCLS  16
#define TOPK  20
#define CB    640           // cols per score panel
#define NCT   8             // panels == 8 XCDs (panel-per-XCD alignment)
#define RB    32            // rows per score block (2 groups of 16; T reused)
#define NTPAD (NCT * CB)    // 5120
#define NTGT  (NTPAD + NTEST) // 10120 scoring targets
#define CCAP  512           // per-row candidate cap (8 panels x <=64)

typedef __attribute__((ext_vector_type(8))) short short8v;
typedef __attribute__((ext_vector_type(4))) short short4v;
typedef __attribute__((ext_vector_type(4))) float f32x4;

// swizzled score-LDS index, stride 640, r in [0,16).
__device__ inline int swz(int r, int c) {
  int cc = c + 4 * r;
  cc = (cc < CB) ? cc : cc - CB;
  return r * CB + cc;
}

// ---------------- bf16 split helpers ----------------
__device__ inline void splitbf(float x, unsigned short& h, unsigned short& l) {
  unsigned u = __float_as_uint(x);
  unsigned hb = (u + 0x7fffu + ((u >> 16) & 1u)) >> 16;    // RNE to bf16
  float hf = __uint_as_float(hb << 16);
  float r = x - hf;
  unsigned ur = __float_as_uint(r);
  unsigned lb = (ur + 0x7fffu + ((ur >> 16) & 1u)) >> 16;
  h = (unsigned short)hb; l = (unsigned short)lb;
}

__device__ inline void split8(float4 a0, float4 a1, short8v& h, short8v& l) {
  unsigned short hh, ll;
  splitbf(a0.x, hh, ll); h[0] = (short)hh; l[0] = (short)ll;
  splitbf(a0.y, hh, ll); h[1] = (short)hh; l[1] = (short)ll;
  splitbf(a0.z, hh, ll); h[2] = (short)hh; l[2] = (short)ll;
  splitbf(a0.w, hh, ll); h[3] = (short)hh; l[3] = (short)ll;
  splitbf(a1.x, hh, ll); h[4] = (short)hh; l[4] = (short)ll;
  splitbf(a1.y, hh, ll); h[5] = (short)hh; l[5] = (short)ll;
  splitbf(a1.z, hh, ll); h[6] = (short)hh; l[6] = (short)ll;
  splitbf(a1.w, hh, ll); h[7] = (short)hh; l[7] = (short)ll;
}

// -------- fused prep: split W1,W2 + lab gather + ccnt zero + dst histogram --
__global__ __launch_bounds__(256)
void prep_hist(const float* __restrict__ W1, unsigned short* __restrict__ WT1hi,
               unsigned short* __restrict__ WT1lo,
               const float* __restrict__ W2, unsigned short* __restrict__ WT2hi,
               unsigned short* __restrict__ WT2lo,
               const float* __restrict__ onehot, const int* __restrict__ itr,
               float* __restrict__ lab, int* __restrict__ ccnt,
               const int* __restrict__ edst, int* __restrict__ cursor) {
  int gid = blockIdx.x * 256 + threadIdx.x;
  if (gid < NFEAT * 128) {
    int n = gid / NFEAT, k = gid - n * NFEAT;
    unsigned short h, l;
    splitbf(W1[(size_t)k * 128 + n], h, l);
    WT1hi[gid] = h; WT1lo[gid] = l;
  } else if (gid < NFEAT * 128 + NHID * 128) {
    int i = gid - NFEAT * 128;
    int n = i / NHID, k = i - n * NHID;
    unsigned short h, l;
    splitbf(W2[(size_t)k * 128 + n], h, l);
    WT2hi[i] = h; WT2lo[i] = l;
  } else if (gid < NFEAT * 128 + NHID * 128 + NTRAIN * NCLS) {
    int i = gid - NFEAT * 128 - NHID * 128;
    int j = i >> 4, c = i & 15;
    lab[i] = onehot[(size_t)itr[j] * NCLS + c];
  } else if (gid < NFEAT * 128 + NHID * 128 + NTRAIN * NCLS + NTEST) {
    ccnt[gid - NFEAT * 128 - NHID * 128 - NTRAIN * NCLS] = 0;
  } else if (gid < NFEAT * 128 + NHID * 128 + NTRAIN * NCLS + NTEST + NEDGE) {
    int e = gid - NFEAT * 128 - NHID * 128 - NTRAIN * NCLS - NTEST;
    atomicAdd(&cursor[edst[e]], 1);
  }
}

// single-block exclusive scan, 1024 threads
#define SCHUNK 49
__global__ __launch_bounds__(1024)
void scan_cnt(int* __restrict__ cnt) {
  __shared__ int part[1024];
  const int t = threadIdx.x;
  const int base = t * SCHUNK;
  int s = 0;
  {
    int idx = base;
#pragma unroll
    for (int i = 0; i < 12; ++i, idx += 4) {
      if (idx + 3 < NNODE) {
        int4 v = *reinterpret_cast<const int4*>(&cnt[idx]);
        s += v.x + v.y + v.z + v.w;
      } else {
        for (int j = 0; j < 4; ++j) if (idx + j < NNODE) s += cnt[idx + j];
      }
    }
    if (idx < NNODE) s += cnt[idx];
  }
  part[t] = s;
  __syncthreads();
  for (int off = 1; off < 1024; off <<= 1) {
    int v = (t >= off) ? part[t - off] : 0;
    __syncthreads();
    part[t] += v;
    __syncthreads();
  }
  int run = part[t] - s;
  {
    int idx = base;
#pragma unroll
    for (int i = 0; i < 12; ++i, idx += 4) {
      if (idx + 3 < NNODE) {
        int4 v = *reinterpret_cast<const int4*>(&cnt[idx]);
        int4 o;
        o.x = run; run += v.x; o.y = run; run += v.y;
        o.z = run; run += v.z; o.w = run; run += v.w;
        *reinterpret_cast<int4*>(&cnt[idx]) = o;
      } else {
        for (int j = 0; j < 4; ++j)
          if (idx + j < NNODE) { int c = cnt[idx + j]; cnt[idx + j] = run; run += c; }
      }
    }
    if (idx < NNODE) { int c = cnt[idx]; cnt[idx] = run; run += c; }
  }
}

// ---------------- gemm1: X1 = feat @ W1 (MFMA, bf16 3-term split) ----------
// (separate dispatch this round: isolate gemm1 vs fill_csr in the profile
// after r12-r16 showed 4 structure changes with no win on the fused 92us)
__global__ __launch_bounds__(256)
void gemm1(const float* __restrict__ A, const unsigned short* __restrict__ WThi,
           const unsigned short* __restrict__ WTlo, float* __restrict__ C) {
  const int tid = threadIdx.x;
  const int w = tid >> 6, lane = tid & 63;
  const int m0 = blockIdx.x * 64 + w * 16;
  int arow = m0 + (lane & 15); if (arow > NNODE - 1) arow = NNODE - 1;
  const int koff = (lane >> 4) * 8;

  f32x4 acc[8];
#pragma unroll
  for (int t = 0; t < 8; ++t) acc[t] = {0.f, 0.f, 0.f, 0.f};

#pragma unroll
  for (int ks = 0; ks < 8; ++ks) {
    const float* ap = &A[(size_t)arow * NFEAT + ks * 32 + koff];
    float4 a0 = *reinterpret_cast<const float4*>(ap);
    float4 a1 = *reinterpret_cast<const float4*>(ap + 4);
    short8v ah, al;
    split8(a0, a1, ah, al);
#pragma unroll
    for (int t = 0; t < 8; ++t) {
      size_t bo = (size_t)(t * 16 + (lane & 15)) * NFEAT + ks * 32 + koff;
      short8v bh = *reinterpret_cast<const short8v*>(&WThi[bo]);
      short8v bl = *reinterpret_cast<const short8v*>(&WTlo[bo]);
      acc[t] = __builtin_amdgcn_mfma_f32_16x16x32_bf16(ah, bh, acc[t], 0, 0, 0);
      acc[t] = __builtin_amdgcn_mfma_f32_16x16x32_bf16(ah, bl, acc[t], 0, 0, 0);
      acc[t] = __builtin_amdgcn_mfma_f32_16x16x32_bf16(al, bh, acc[t], 0, 0, 0);
    }
  }
  const int crow0 = m0 + (lane >> 4) * 4;
#pragma unroll
  for (int j = 0; j < 4; ++j) {
    int row = crow0 + j;
    if (row < NNODE) {
#pragma unroll
      for (int t = 0; t < 8; ++t)
        C[(size_t)row * 128 + t * 16 + (lane & 15)] = acc[t][j];
    }
  }
}

// ---------------- fill_csr (simple r12 form, separate dispatch) -------------
__global__ __launch_bounds__(256)
void fill_csr(const int* __restrict__ esrc, const int* __restrict__ edst,
              const float* __restrict__ ew, int* __restrict__ cursor,
              int2* __restrict__ packed) {
  int e = blockIdx.x * 256 + threadIdx.x;
  if (e < NEDGE) {
    int d = edst[e];
    int p = atomicAdd(&cursor[d], 1);
    packed[p] = make_int2(esrc[e], __float_as_int(ew[e]));
  }
}

// ---------------- propagate (full, fp32 out): 1 wave/node, float4/lane ------
__global__ __launch_bounds__(256)
void gather_nodes(const float* __restrict__ X, float* __restrict__ out,
                  const int* __restrict__ endoff, const int2* __restrict__ packed,
                  const float* __restrict__ bias) {
  const int tid = threadIdx.x;
  const int node = blockIdx.x * 4 + (tid >> 6);
  const int lane = tid & 63;
  const int half = lane >> 5, c4 = lane & 31;
  const int beg = node ? endoff[node - 1] : 0;
  const int end = endoff[node];
  const float4* X4 = reinterpret_cast<const float4*>(X);
  float4 a0 = {0.f,0.f,0.f,0.f}, a1 = {0.f,0.f,0.f,0.f};
  float4 a2 = {0.f,0.f,0.f,0.f}, a3 = {0.f,0.f,0.f,0.f};
  int e = beg + half;
  for (; e + 6 < end; e += 8) {
    int2 p0 = packed[e],     p1 = packed[e + 2];
    int2 p2 = packed[e + 4], p3 = packed[e + 6];
    float4 x0 = X4[(size_t)p0.x * 32 + c4];
    float4 x1 = X4[(size_t)p1.x * 32 + c4];
    float4 x2 = X4[(size_t)p2.x * 32 + c4];
    float4 x3 = X4[(size_t)p3.x * 32 + c4];
    float w0 = __int_as_float(p0.y), w1 = __int_as_float(p1.y);
    float w2 = __int_as_float(p2.y), w3 = __int_as_float(p3.y);
    a0.x += w0*x0.x; a0.y += w0*x0.y; a0.z += w0*x0.z; a0.w += w0*x0.w;
    a1.x += w1*x1.x; a1.y += w1*x1.y; a1.z += w1*x1.z; a1.w += w1*x1.w;
    a2.x += w2*x2.x; a2.y += w2*x2.y; a2.z += w2*x2.z; a2.w += w2*x2.w;
    a3.x += w3*x3.x; a3.y += w3*x3.y; a3.z += w3*x3.z; a3.w += w3*x3.w;
  }
  for (; e < end; e += 2) {
    int2 p = packed[e];
    float4 x = X4[(size_t)p.x * 32 + c4];
    float w = __int_as_float(p.y);
    a0.x += w*x.x; a0.y += w*x.y; a0.z += w*x.z; a0.w += w*x.w;
  }
  a0.x += a1.x + a2.x + a3.x; a0.y += a1.y + a2.y + a3.y;
  a0.z += a1.z + a2.z + a3.z; a0.w += a1.w + a2.w + a3.w;
  a0.x += __shfl_xor(a0.x, 32); a0.y += __shfl_xor(a0.y, 32);
  a0.z += __shfl_xor(a0.z, 32); a0.w += __shfl_xor(a0.w, 32);
  if (half == 0) {
    float4 b = reinterpret_cast<const float4*>(bias)[c4];
    a0.x += b.x; a0.y += b.y; a0.z += b.z; a0.w += b.w;
    reinterpret_cast<float4*>(out)[(size_t)node * 32 + c4] = a0;
  }
}

// ------- targeted propagate of relu(h): g[tgt] = sum_e w * relu(h[src]) -----
__global__ __launch_bounds__(256)
void gather_targets2(const float* __restrict__ H, const int* __restrict__ endoff,
                     const int2* __restrict__ packed,
                     const int* __restrict__ itr, const int* __restrict__ ite,
                     float* __restrict__ g) {
  const int tid = threadIdx.x;
  const int tgt = blockIdx.x * 4 + (tid >> 6);
  const int lane = tid & 63;
  const int half = lane >> 5, c4 = lane & 31;
  const bool isQ = tgt >= NTPAD;
  const int j = isQ ? tgt - NTPAD : tgt;
  int node = -1;
  if (isQ) { if (j < NTEST) node = ite[j]; }
  else if (j < NTRAIN) node = itr[j];

  float4 a0 = {0.f, 0.f, 0.f, 0.f};
  if (node >= 0) {                       // wave-uniform branch
    const int beg = node ? endoff[node - 1] : 0;
    const int end = endoff[node];
    const float4* X4 = reinterpret_cast<const float4*>(H);
    float4 a1 = {0.f,0.f,0.f,0.f}, a2 = {0.f,0.f,0.f,0.f}, a3 = {0.f,0.f,0.f,0.f};
    int e = beg + half;
    for (; e + 6 < end; e += 8) {
      int2 p0 = packed[e],     p1 = packed[e + 2];
      int2 p2 = packed[e + 4], p3 = packed[e + 6];
      float4 x0 = X4[(size_t)p0.x * 32 + c4];
      float4 x1 = X4[(size_t)p1.x * 32 + c4];
      float4 x2 = X4[(size_t)p2.x * 32 + c4];
      float4 x3 = X4[(size_t)p3.x * 32 + c4];
      float w0 = __int_as_float(p0.y), w1 = __int_as_float(p1.y);
      float w2 = __int_as_float(p2.y), w3 = __int_as_float(p3.y);
      a0.x += w0*fmaxf(x0.x,0.f); a0.y += w0*fmaxf(x0.y,0.f);
      a0.z += w0*fmaxf(x0.z,0.f); a0.w += w0*fmaxf(x0.w,0.f);
      a1.x += w1*fmaxf(x1.x,0.f); a1.y += w1*fmaxf(x1.y,0.f);
      a1.z += w1*fmaxf(x1.z,0.f); a1.w += w1*fmaxf(x1.w,0.f);
      a2.x += w2*fmaxf(x2.x,0.f); a2.y += w2*fmaxf(x2.y,0.f);
      a2.z += w2*fmaxf(x2.z,0.f); a2.w += w2*fmaxf(x2.w,0.f);
      a3.x += w3*fmaxf(x3.x,0.f); a3.y += w3*fmaxf(x3.y,0.f);
      a3.z += w3*fmaxf(x3.z,0.f); a3.w += w3*fmaxf(x3.w,0.f);
    }
    for (; e < end; e += 2) {
      int2 p = packed[e];
      float4 x = X4[(size_t)p.x * 32 + c4];
      float w = __int_as_float(p.y);
      a0.x += w*fmaxf(x.x,0.f); a0.y += w*fmaxf(x.y,0.f);
      a0.z += w*fmaxf(x.z,0.f); a0.w += w*fmaxf(x.w,0.f);
    }
    a0.x += a1.x + a2.x + a3.x; a0.y += a1.y + a2.y + a3.y;
    a0.z += a1.z + a2.z + a3.z; a0.w += a1.w + a2.w + a3.w;
    a0.x += __shfl_xor(a0.x, 32); a0.y += __shfl_xor(a0.y, 32);
    a0.z += __shfl_xor(a0.z, 32); a0.w += __shfl_xor(a0.w, 32);
  }
  if (half == 0 && tgt < NTGT)
    reinterpret_cast<float4*>(g)[(size_t)tgt * 32 + c4] = a0;
}

// ------- mini GEMM: (g @ W2) + b2 over 10120 target rows -> bf16-split T/Q --
__global__ __launch_bounds__(256)
void mini_gemm(const float* __restrict__ A, const unsigned short* __restrict__ WThi,
               const unsigned short* __restrict__ WTlo, const float* __restrict__ b2,
               unsigned short* __restrict__ Thi, unsigned short* __restrict__ Tlo,
               unsigned short* __restrict__ Qhi, unsigned short* __restrict__ Qlo) {
  const int tid = threadIdx.x;
  const int w = tid >> 6, lane = tid & 63;
  const int m0 = blockIdx.x * 64 + w * 16;
  int arow = m0 + (lane & 15); if (arow > NTGT - 1) arow = NTGT - 1;
  const int koff = (lane >> 4) * 8;

  f32x4 acc[8];
#pragma unroll
  for (int t = 0; t < 8; ++t) acc[t] = {0.f, 0.f, 0.f, 0.f};

#pragma unroll
  for (int ks = 0; ks < 4; ++ks) {
    const float* ap = &A[(size_t)arow * NHID + ks * 32 + koff];
    float4 a0 = *reinterpret_cast<const float4*>(ap);
    float4 a1 = *reinterpret_cast<const float4*>(ap + 4);
    short8v ah, al;
    split8(a0, a1, ah, al);
#pragma unroll
    for (int t = 0; t < 8; ++t) {
      size_t bo = (size_t)(t * 16 + (lane & 15)) * NHID + ks * 32 + koff;
      short8v bh = *reinterpret_cast<const short8v*>(&WThi[bo]);
      short8v bl = *reinterpret_cast<const short8v*>(&WTlo[bo]);
      acc[t] = __builtin_amdgcn_mfma_f32_16x16x32_bf16(ah, bh, acc[t], 0, 0, 0);
      acc[t] = __builtin_amdgcn_mfma_f32_16x16x32_bf16(ah, bl, acc[t], 0, 0, 0);
      acc[t] = __builtin_amdgcn_mfma_f32_16x16x32_bf16(al, bh, acc[t], 0, 0, 0);
    }
  }
  const int crow0 = m0 + (lane >> 4) * 4;
#pragma unroll
  for (int j = 0; j < 4; ++j) {
    int row = crow0 + j;
    if (row < NTGT) {
#pragma unroll
      for (int t = 0; t < 8; ++t) {
        int col = t * 16 + (lane & 15);
        float val = acc[t][j] + b2[col];
        unsigned short h, l;
        splitbf(val, h, l);
        if (row < NTPAD) {
          Thi[(size_t)row * 128 + col] = h;
          Tlo[(size_t)row * 128 + col] = l;
        } else {
          Qhi[(size_t)(row - NTPAD) * 128 + col] = h;
          Qlo[(size_t)(row - NTPAD) * 128 + col] = l;
        }
      }
    }
  }
}

// ---------------- MFMA score: 32 rows/block, T-panel read once --------------
__global__ __launch_bounds__(512)
void score_mfma(const unsigned short* __restrict__ Qhi, const unsigned short* __restrict__ Qlo,
                const unsigned short* __restrict__ Thi, const unsigned short* __restrict__ Tlo,
                int* __restrict__ ccnt, float* __restrict__ candv, int* __restrict__ candi) {
  __shared__ float s[2 * 16 * CB];     // 80 KB
  const int tid = threadIdx.x;
  const int w = tid >> 6, lane = tid & 63;   // w in 0..7
  const int r0 = (blockIdx.x >> 3) * RB;
  const int j0 = (blockIdx.x & 7) * CB;

  int arow0 = r0 + (lane & 15);      if (arow0 > NTEST - 1) arow0 = NTEST - 1;
  int arow1 = r0 + 16 + (lane & 15); if (arow1 > NTEST - 1) arow1 = NTEST - 1;
  const int koff = (lane >> 4) * 8;
  short8v ah0[4], al0[4], ah1[4], al1[4];
#pragma unroll
  for (int ks = 0; ks < 4; ++ks) {
    ah0[ks] = *reinterpret_cast<const short8v*>(&Qhi[(size_t)arow0 * 128 + ks * 32 + koff]);
    al0[ks] = *reinterpret_cast<const short8v*>(&Qlo[(size_t)arow0 * 128 + ks * 32 + koff]);
    ah1[ks] = *reinterpret_cast<const short8v*>(&Qhi[(size_t)arow1 * 128 + ks * 32 + koff]);
    al1[ks] = *reinterpret_cast<const short8v*>(&Qlo[(size_t)arow1 * 128 + ks * 32 + koff]);
  }

#pragma unroll
  for (int t = 0; t < 5; ++t) {
    int colbase = w * 80 + t * 16;
    int col = j0 + colbase + (lane & 15);            // < NTPAD always
    const unsigned short* bh = &Thi[(size_t)col * 128 + koff];
    const unsigned short* bl = &Tlo[(size_t)col * 128 + koff];
    f32x4 a0 = {0.f, 0.f, 0.f, 0.f};
    f32x4 a1 = {0.f, 0.f, 0.f, 0.f};
#pragma unroll
    for (int ks = 0; ks < 4; ++ks) {
      short8v bhv = *reinterpret_cast<const short8v*>(&bh[ks * 32]);
      short8v blv = *reinterpret_cast<const short8v*>(&bl[ks * 32]);
      a0 = __builtin_amdgcn_mfma_f32_16x16x32_bf16(ah0[ks], bhv, a0, 0, 0, 0);
      a1 = __builtin_amdgcn_mfma_f32_16x16x32_bf16(ah1[ks], bhv, a1, 0, 0, 0);
      a0 = __builtin_amdgcn_mfma_f32_16x16x32_bf16(ah0[ks], blv, a0, 0, 0, 0);
      a1 = __builtin_amdgcn_mfma_f32_16x16x32_bf16(ah1[ks], blv, a1, 0, 0, 0);
      a0 = __builtin_amdgcn_mfma_f32_16x16x32_bf16(al0[ks], bhv, a0, 0, 0, 0);
      a1 = __builtin_amdgcn_mfma_f32_16x16x32_bf16(al1[ks], bhv, a1, 0, 0, 0);
    }
    int sc = colbase + (lane & 15);
    int sr = (lane >> 4) * 4;
#pragma unroll
    for (int r = 0; r < 4; ++r) s[swz(sr + r, sc)] = a0[r];
#pragma unroll
    for (int r = 0; r < 4; ++r) s[16 * CB + swz(sr + r, sc)] = a1[r];
  }
  __syncthreads();

  const unsigned long long ltm = ((unsigned long long)1 << lane) - 1;

#pragma unroll
  for (int g = 0; g < 2; ++g) {
    const float* sg = s + g * 16 * CB;
#pragma unroll
    for (int r = 0; r < 2; ++r) {
      const int m = w * 2 + r;
      const int row = r0 + g * 16 + m;
      if (row >= NTEST) continue;
      float v[10];
#pragma unroll
      for (int k = 0; k < 10; ++k) {
        int c = lane + 64 * k;
        v[k] = (j0 + c < NTRAIN) ? sg[swz(m, c)] : -INFINITY;
      }
      float t0 = fmaxf(v[0], v[1]), t1 = fmaxf(v[2], v[3]);
      float t2 = fmaxf(v[4], v[5]), t3 = fmaxf(v[6], v[7]);
      float sv = fmaxf(fmaxf(fmaxf(t0, t1), fmaxf(t2, t3)), fmaxf(v[8], v[9]));
#pragma unroll
      for (int k = 2; k <= 64; k <<= 1) {
#pragma unroll
        for (int j = k >> 1; j > 0; j >>= 1) {
          float ov = __shfl_xor(sv, j);
          bool keepMax = ((lane & j) == 0) == ((lane & k) == 0 || k == 64);
          sv = keepMax ? fmaxf(sv, ov) : fminf(sv, ov);
        }
      }
      float T = __shfl(sv, 19);       // 20th-largest lane-max

      int myo[10];
      int tot = 0;
#pragma unroll
      for (int k = 0; k < 10; ++k) {
        unsigned long long mk = __ballot(v[k] >= T);
        myo[k] = tot + (int)__popcll(mk & ltm);
        tot += (int)__popcll(mk);
      }
      if (tot <= 64) {                // typical tot ~ 22
        int base = 0;
        if (lane == 0) base = atomicAdd(&ccnt[row], tot);
        base = __shfl(base, 0);
        float* cv = candv + (size_t)row * CCAP + base;
        int*   ci = candi + (size_t)row * CCAP + base;
#pragma unroll
        for (int k = 0; k < 10; ++k) {
          if (v[k] >= T) { cv[myo[k]] = v[k]; ci[myo[k]] = j0 + lane + 64 * k; }
        }
      } else {                        // rare dense path: exact top-20
        float selv = 0.f; int seli = 0;
#pragma unroll
        for (int it = 0; it < TOPK; ++it) {
          float bv = v[0]; int bk = 0;
#pragma unroll
          for (int k = 1; k < 10; ++k)
            if (v[k] > bv) { bv = v[k]; bk = k; }
          int bj = lane + 64 * bk;
#pragma unroll
          for (int off = 1; off < 64; off <<= 1) {
            float ov = __shfl_xor(bv, off);
            int   oj = __shfl_xor(bj, off);
            if (ov > bv || (ov == bv && oj < bj)) { bv = ov; bj = oj; }
          }
          if (lane == it) { selv = bv; seli = j0 + bj; }
          int ck = bj >> 6;
          if ((bj & 63) == lane) {
#pragma unroll
            for (int k = 0; k < 10; ++k)
              if (k == ck) v[k] = -INFINITY;
          }
        }
        int base = 0;
        if (lane == 0) base = atomicAdd(&ccnt[row], TOPK);
        base = __shfl(base, 0);
        if (lane < TOPK) {
          candv[(size_t)row * CCAP + base + lane] = selv;
          candi[(size_t)row * CCAP + base + lane] = seli;
        }
      }
    }
  }
}

// 64-lane bitonic sort, descending by (value, then ascending index)
__device__ inline void sort64_vi(float& v, int& idx, int lane) {
#pragma unroll
  for (int k = 2; k <= 64; k <<= 1) {
#pragma unroll
    for (int j = k >> 1; j > 0; j >>= 1) {
      float ov = __shfl_xor(v, j);
      int   oi = __shfl_xor(idx, j);
      bool first = (v > ov) || (v == ov && idx < oi);
      bool keepMine = (((lane & j) == 0) == ((lane & k) == 0 || k == 64)) ? first : !first;
      if (!keepMine) { v = ov; idx = oi; }
    }
  }
}

// ---------------- merge: streaming bitonic top-20 + softmax + preds ----------
__global__ __launch_bounds__(256)
void merge_topk(const float* __restrict__ candv, const int* __restrict__ candi,
                const int* __restrict__ ccnt, const float* __restrict__ lab,
                float* __restrict__ out) {
  const int tid = threadIdx.x;
  const int wv = tid >> 6, lane = tid & 63;
  const int row = blockIdx.x * 4 + wv;
  const size_t base = (size_t)row * CCAP;
  const int C = ccnt[row];

  float v = -INFINITY; int idx = INT_MAX;
  int take = C < 64 ? C : 64;
  if (lane < take) { v = candv[base + lane]; idx = candi[base + lane]; }
  sort64_vi(v, idx, lane);
  int consumed = take;
  while (consumed < C) {
    int n = C - consumed; if (n > 44) n = 44;
    if (lane >= TOPK) {
      int p = lane - TOPK;
      if (p < n) { v = candv[base + consumed + p]; idx = candi[base + consumed + p]; }
      else       { v = -INFINITY; idx = INT_MAX; }
    }
    sort64_vi(v, idx, lane);
    consumed += n;
  }
  float mx = __shfl(v, 0);
  float wgt = (lane < TOPK) ? expf(v - mx) : 0.f;
  float sum = wgt;
#pragma unroll
  for (int off = 1; off < 64; off <<= 1) sum += __shfl_xor(sum, off);

  float acc = 0.f;
#pragma unroll
  for (int i = 0; i < TOPK; ++i) {
    float wi = __shfl(wgt, i);
    int   ji = __shfl(idx, i);
    if (lane < NCLS) acc += wi * lab[(size_t)ji * NCLS + lane];
  }
  if (lane < NCLS) out[(size_t)row * NCLS + lane] = acc / sum;
}

extern "C" void kernel_launch(void* const* d_in, const int* in_sizes, int n_in,
                              void* d_out, int out_size, void* d_ws, size_t ws_size,
                              hipStream_t stream) {
  const float* feat   = (const float*)d_in[0];
  const float* ew     = (const float*)d_in[1];
  const float* onehot = (const float*)d_in[2];
  const float* W1     = (const float*)d_in[3];
  const float* b1     = (const float*)d_in[4];
  const float* W2     = (const float*)d_in[5];
  const float* b2     = (const float*)d_in[6];
  const int*   ei     = (const int*)d_in[7];
  const int*   itr    = (const int*)d_in[8];
  const int*   ite    = (const int*)d_in[9];
  float* out = (float*)d_out;
  float* ws  = (float*)d_ws;

  float* bufA   = ws;                                  // [NNODE][128] X1; later T/Q + g
  float* bufH   = bufA + (size_t)NNODE * NHID;         // [NNODE][128] h; later candidates
  int*   cursor = (int*)(bufH + (size_t)NNODE * NHID); // [NNODE]
  int2*  packed = (int2*)(cursor + ((NNODE + 15) & ~15)); // [NEDGE]
  unsigned short* WT1hi = (unsigned short*)(packed + NEDGE);    // [128][256]
  unsigned short* WT1lo = WT1hi + 128 * NFEAT;
  unsigned short* WT2hi = WT1lo + 128 * NFEAT;                  // [128][128]
  unsigned short* WT2lo = WT2hi + 128 * NHID;
  float* lab  = (float*)(WT2lo + 128 * NHID);                   // [5000][16]
  int*   ccnt = (int*)(lab + (size_t)NTRAIN * NCLS);            // [5000]
  // after gather_nodes X1 (bufA) is dead: T/Q (5.2MB) then g (5.2MB) live there
  unsigned short* Thi = (unsigned short*)bufA;                  // [NTPAD][128]
  unsigned short* Tlo = Thi + (size_t)NTPAD * NHID;
  unsigned short* Qhi = Tlo + (size_t)NTPAD * NHID;             // [NTEST][128]
  unsigned short* Qlo = Qhi + (size_t)NTEST * NHID;
  float* g    = (float*)(Qlo + (size_t)NTEST * NHID);           // [NTGT][128] fp32
  // candidates live in bufH (h dead after gather_targets2): 2 x 10.2 MB
  float* candv = bufH;                                          // [5000][512]
  int*   candi = (int*)(bufH + (size_t)NTEST * CCAP);

  const int* esrc = ei;
  const int* edst = ei + NEDGE;

  // cursor zero (async memset) + fused prep/hist + scan + gemm1 + fill (split)
  hipMemsetAsync(cursor, 0, NNODE * sizeof(int), stream);
  int ptot = NFEAT * 128 + NHID * 128 + NTRAIN * NCLS + NTEST + NEDGE;
  prep_hist<<<(ptot + 255) / 256, 256, 0, stream>>>(
      W1, WT1hi, WT1lo, W2, WT2hi, WT2lo, onehot, itr, lab, ccnt, edst, cursor);
  scan_cnt<<<1, 1024, 0, stream>>>(cursor);
  gemm1<<<(NNODE + 63) / 64, 256, 0, stream>>>(feat, WT1hi, WT1lo, bufA);
  fill_csr<<<(NEDGE + 255) / 256, 256, 0, stream>>>(esrc, edst, ew, cursor, packed);

  // h = propagate(X1)+b1 (full); g = propagate_targets(relu(h)); T/Q = g@W2+b2
  gather_nodes<<<NNODE / 4, 256, 0, stream>>>(bufA, bufH, cursor, packed, b1);
  gather_targets2<<<(NTGT + 3) / 4, 256, 0, stream>>>(bufH, cursor, packed, itr, ite, g);
  mini_gemm<<<(NTGT + 63) / 64, 256, 0, stream>>>(
      g, WT2hi, WT2lo, b2, Thi, Tlo, Qhi, Qlo);

  // scoring (panel-per-XCD 1D grid, 32 rows/block)
  score_mfma<<<((NTEST + RB - 1) / RB) * NCT, 512, 0, stream>>>(
      Qhi, Qlo, Thi, Tlo, ccnt, candv, candi);
  merge_topk<<<NTEST / 4, 256, 0, stream>>>(candv, candi, ccnt, lab, out);
}

// Round 18
// 324.522 us; speedup vs baseline: 1.1418x; 1.1418x over previous
//
#include <hip/hip_runtime.h>
#include <math.h>
#include <limits.h>

#define NNODE 50000
#define NEDGE 800000
#define NFEAT 256
#define NHID  128
#define NTEST 5000
#define NTRAIN 5000
#define NCLS  16
#define TOPK  20
#define CB    640           // cols per score panel
#define NCT   8             // panels == 8 XCDs (panel-per-XCD alignment)
#define RB    32            // rows per score block (2 groups of 16; T reused)
#define NTPAD (NCT * CB)    // 5120
#define NTGT  (NTPAD + NTEST) // 10120 scoring targets
#define CCAP  512           // per-row candidate cap (8 panels x <=64)
#define GB1   ((NNODE + 63) / 64)   // gemm1 blocks (782)
#define FB1   ((NEDGE + 255) / 256) // fill_csr blocks (3125)

typedef __attribute__((ext_vector_type(8))) short short8v;
typedef __attribute__((ext_vector_type(4))) short short4v;
typedef __attribute__((ext_vector_type(4))) float f32x4;

// swizzled score-LDS index, stride 640, r in [0,16).
// shift = 4*r: conflict-free writes and reads (r10/r11: verified 0).
__device__ inline int swz(int r, int c) {
  int cc = c + 4 * r;
  cc = (cc < CB) ? cc : cc - CB;
  return r * CB + cc;
}

// ---------------- bf16 split helpers ----------------
__device__ inline void splitbf(float x, unsigned short& h, unsigned short& l) {
  unsigned u = __float_as_uint(x);
  unsigned hb = (u + 0x7fffu + ((u >> 16) & 1u)) >> 16;    // RNE to bf16
  float hf = __uint_as_float(hb << 16);
  float r = x - hf;
  unsigned ur = __float_as_uint(r);
  unsigned lb = (ur + 0x7fffu + ((ur >> 16) & 1u)) >> 16;
  h = (unsigned short)hb; l = (unsigned short)lb;
}

__device__ inline void split8(float4 a0, float4 a1, short8v& h, short8v& l) {
  unsigned short hh, ll;
  splitbf(a0.x, hh, ll); h[0] = (short)hh; l[0] = (short)ll;
  splitbf(a0.y, hh, ll); h[1] = (short)hh; l[1] = (short)ll;
  splitbf(a0.z, hh, ll); h[2] = (short)hh; l[2] = (short)ll;
  splitbf(a0.w, hh, ll); h[3] = (short)hh; l[3] = (short)ll;
  splitbf(a1.x, hh, ll); h[4] = (short)hh; l[4] = (short)ll;
  splitbf(a1.y, hh, ll); h[5] = (short)hh; l[5] = (short)ll;
  splitbf(a1.z, hh, ll); h[6] = (short)hh; l[6] = (short)ll;
  splitbf(a1.w, hh, ll); h[7] = (short)hh; l[7] = (short)ll;
}

// -------- fused prep: split W1,W2 + lab gather + ccnt zero + dst histogram --
__global__ __launch_bounds__(256)
void prep_hist(const float* __restrict__ W1, unsigned short* __restrict__ WT1hi,
               unsigned short* __restrict__ WT1lo,
               const float* __restrict__ W2, unsigned short* __restrict__ WT2hi,
               unsigned short* __restrict__ WT2lo,
               const float* __restrict__ onehot, const int* __restrict__ itr,
               float* __restrict__ lab, int* __restrict__ ccnt,
               const int* __restrict__ edst, int* __restrict__ cursor) {
  int gid = blockIdx.x * 256 + threadIdx.x;
  if (gid < NFEAT * 128) {
    int n = gid / NFEAT, k = gid - n * NFEAT;
    unsigned short h, l;
    splitbf(W1[(size_t)k * 128 + n], h, l);
    WT1hi[gid] = h; WT1lo[gid] = l;
  } else if (gid < NFEAT * 128 + NHID * 128) {
    int i = gid - NFEAT * 128;
    int n = i / NHID, k = i - n * NHID;
    unsigned short h, l;
    splitbf(W2[(size_t)k * 128 + n], h, l);
    WT2hi[i] = h; WT2lo[i] = l;
  } else if (gid < NFEAT * 128 + NHID * 128 + NTRAIN * NCLS) {
    int i = gid - NFEAT * 128 - NHID * 128;
    int j = i >> 4, c = i & 15;
    lab[i] = onehot[(size_t)itr[j] * NCLS + c];
  } else if (gid < NFEAT * 128 + NHID * 128 + NTRAIN * NCLS + NTEST) {
    ccnt[gid - NFEAT * 128 - NHID * 128 - NTRAIN * NCLS] = 0;
  } else if (gid < NFEAT * 128 + NHID * 128 + NTRAIN * NCLS + NTEST + NEDGE) {
    int e = gid - NFEAT * 128 - NHID * 128 - NTRAIN * NCLS - NTEST;
    atomicAdd(&cursor[edst[e]], 1);
  }
}

// single-block exclusive scan, 1024 threads
#define SCHUNK 49
__global__ __launch_bounds__(1024)
void scan_cnt(int* __restrict__ cnt) {
  __shared__ int part[1024];
  const int t = threadIdx.x;
  const int base = t * SCHUNK;
  int s = 0;
  {
    int idx = base;
#pragma unroll
    for (int i = 0; i < 12; ++i, idx += 4) {
      if (idx + 3 < NNODE) {
        int4 v = *reinterpret_cast<const int4*>(&cnt[idx]);
        s += v.x + v.y + v.z + v.w;
      } else {
        for (int j = 0; j < 4; ++j) if (idx + j < NNODE) s += cnt[idx + j];
      }
    }
    if (idx < NNODE) s += cnt[idx];
  }
  part[t] = s;
  __syncthreads();
  for (int off = 1; off < 1024; off <<= 1) {
    int v = (t >= off) ? part[t - off] : 0;
    __syncthreads();
    part[t] += v;
    __syncthreads();
  }
  int run = part[t] - s;
  {
    int idx = base;
#pragma unroll
    for (int i = 0; i < 12; ++i, idx += 4) {
      if (idx + 3 < NNODE) {
        int4 v = *reinterpret_cast<const int4*>(&cnt[idx]);
        int4 o;
        o.x = run; run += v.x; o.y = run; run += v.y;
        o.z = run; run += v.z; o.w = run; run += v.w;
        *reinterpret_cast<int4*>(&cnt[idx]) = o;
      } else {
        for (int j = 0; j < 4; ++j)
          if (idx + j < NNODE) { int c = cnt[idx + j]; cnt[idx + j] = run; run += c; }
      }
    }
    if (idx < NNODE) { int c = cnt[idx]; cnt[idx] = run; run += c; }
  }
}

// ------- fused: gemm1 (X1 = feat@W1, MFMA) blocks 0..GB1-1; fill_csr after --
// KEEP FUSED: r17 split measured +45us (gemm1's idle-pipe latency profile
// and fill_csr's scatter traffic mutually hide; the pair is near its
// combined floor — r12-r16 single-sided fixes were all neutral/negative).
__global__ __launch_bounds__(256)
void gemm1_fill(const float* __restrict__ A, const unsigned short* __restrict__ WThi,
                const unsigned short* __restrict__ WTlo, float* __restrict__ C,
                const int* __restrict__ esrc, const int* __restrict__ edst,
                const float* __restrict__ ew, int* __restrict__ cursor,
                int2* __restrict__ packed) {
  const int tid = threadIdx.x;
  if (blockIdx.x >= GB1) {                 // ---- fill_csr part ----
    int e = (blockIdx.x - GB1) * 256 + tid;
    if (e < NEDGE) {
      int d = edst[e];
      int p = atomicAdd(&cursor[d], 1);
      packed[p] = make_int2(esrc[e], __float_as_int(ew[e]));
    }
    return;
  }
  // ---- gemm1 part (KT=256, no relu) ----
  const int w = tid >> 6, lane = tid & 63;
  const int m0 = blockIdx.x * 64 + w * 16;
  int arow = m0 + (lane & 15); if (arow > NNODE - 1) arow = NNODE - 1;
  const int koff = (lane >> 4) * 8;

  f32x4 acc[8];
#pragma unroll
  for (int t = 0; t < 8; ++t) acc[t] = {0.f, 0.f, 0.f, 0.f};

#pragma unroll
  for (int ks = 0; ks < 8; ++ks) {
    const float* ap = &A[(size_t)arow * NFEAT + ks * 32 + koff];
    float4 a0 = *reinterpret_cast<const float4*>(ap);
    float4 a1 = *reinterpret_cast<const float4*>(ap + 4);
    short8v ah, al;
    split8(a0, a1, ah, al);
#pragma unroll
    for (int t = 0; t < 8; ++t) {
      size_t bo = (size_t)(t * 16 + (lane & 15)) * NFEAT + ks * 32 + koff;
      short8v bh = *reinterpret_cast<const short8v*>(&WThi[bo]);
      short8v bl = *reinterpret_cast<const short8v*>(&WTlo[bo]);
      acc[t] = __builtin_amdgcn_mfma_f32_16x16x32_bf16(ah, bh, acc[t], 0, 0, 0);
      acc[t] = __builtin_amdgcn_mfma_f32_16x16x32_bf16(ah, bl, acc[t], 0, 0, 0);
      acc[t] = __builtin_amdgcn_mfma_f32_16x16x32_bf16(al, bh, acc[t], 0, 0, 0);
    }
  }
  const int crow0 = m0 + (lane >> 4) * 4;
#pragma unroll
  for (int j = 0; j < 4; ++j) {
    int row = crow0 + j;
    if (row < NNODE) {
#pragma unroll
      for (int t = 0; t < 8; ++t)
        C[(size_t)row * 128 + t * 16 + (lane & 15)] = acc[t][j];
    }
  }
}

// ---------------- propagate (full, fp32 out): 1 wave/node, float4/lane ------
__global__ __launch_bounds__(256)
void gather_nodes(const float* __restrict__ X, float* __restrict__ out,
                  const int* __restrict__ endoff, const int2* __restrict__ packed,
                  const float* __restrict__ bias) {
  const int tid = threadIdx.x;
  const int node = blockIdx.x * 4 + (tid >> 6);
  const int lane = tid & 63;
  const int half = lane >> 5, c4 = lane & 31;
  const int beg = node ? endoff[node - 1] : 0;
  const int end = endoff[node];
  const float4* X4 = reinterpret_cast<const float4*>(X);
  float4 a0 = {0.f,0.f,0.f,0.f}, a1 = {0.f,0.f,0.f,0.f};
  float4 a2 = {0.f,0.f,0.f,0.f}, a3 = {0.f,0.f,0.f,0.f};
  int e = beg + half;
  for (; e + 6 < end; e += 8) {
    int2 p0 = packed[e],     p1 = packed[e + 2];
    int2 p2 = packed[e + 4], p3 = packed[e + 6];
    float4 x0 = X4[(size_t)p0.x * 32 + c4];
    float4 x1 = X4[(size_t)p1.x * 32 + c4];
    float4 x2 = X4[(size_t)p2.x * 32 + c4];
    float4 x3 = X4[(size_t)p3.x * 32 + c4];
    float w0 = __int_as_float(p0.y), w1 = __int_as_float(p1.y);
    float w2 = __int_as_float(p2.y), w3 = __int_as_float(p3.y);
    a0.x += w0*x0.x; a0.y += w0*x0.y; a0.z += w0*x0.z; a0.w += w0*x0.w;
    a1.x += w1*x1.x; a1.y += w1*x1.y; a1.z += w1*x1.z; a1.w += w1*x1.w;
    a2.x += w2*x2.x; a2.y += w2*x2.y; a2.z += w2*x2.z; a2.w += w2*x2.w;
    a3.x += w3*x3.x; a3.y += w3*x3.y; a3.z += w3*x3.z; a3.w += w3*x3.w;
  }
  for (; e < end; e += 2) {
    int2 p = packed[e];
    float4 x = X4[(size_t)p.x * 32 + c4];
    float w = __int_as_float(p.y);
    a0.x += w*x.x; a0.y += w*x.y; a0.z += w*x.z; a0.w += w*x.w;
  }
  a0.x += a1.x + a2.x + a3.x; a0.y += a1.y + a2.y + a3.y;
  a0.z += a1.z + a2.z + a3.z; a0.w += a1.w + a2.w + a3.w;
  a0.x += __shfl_xor(a0.x, 32); a0.y += __shfl_xor(a0.y, 32);
  a0.z += __shfl_xor(a0.z, 32); a0.w += __shfl_xor(a0.w, 32);
  if (half == 0) {
    float4 b = reinterpret_cast<const float4*>(bias)[c4];
    a0.x += b.x; a0.y += b.y; a0.z += b.z; a0.w += b.w;
    reinterpret_cast<float4*>(out)[(size_t)node * 32 + c4] = a0;
  }
}

// ------- targeted propagate of relu(h): g[tgt] = sum_e w * relu(h[src]) -----
__global__ __launch_bounds__(256)
void gather_targets2(const float* __restrict__ H, const int* __restrict__ endoff,
                     const int2* __restrict__ packed,
                     const int* __restrict__ itr, const int* __restrict__ ite,
                     float* __restrict__ g) {
  const int tid = threadIdx.x;
  const int tgt = blockIdx.x * 4 + (tid >> 6);
  const int lane = tid & 63;
  const int half = lane >> 5, c4 = lane & 31;
  const bool isQ = tgt >= NTPAD;
  const int j = isQ ? tgt - NTPAD : tgt;
  int node = -1;
  if (isQ) { if (j < NTEST) node = ite[j]; }
  else if (j < NTRAIN) node = itr[j];

  float4 a0 = {0.f, 0.f, 0.f, 0.f};
  if (node >= 0) {                       // wave-uniform branch
    const int beg = node ? endoff[node - 1] : 0;
    const int end = endoff[node];
    const float4* X4 = reinterpret_cast<const float4*>(H);
    float4 a1 = {0.f,0.f,0.f,0.f}, a2 = {0.f,0.f,0.f,0.f}, a3 = {0.f,0.f,0.f,0.f};
    int e = beg + half;
    for (; e + 6 < end; e += 8) {
      int2 p0 = packed[e],     p1 = packed[e + 2];
      int2 p2 = packed[e + 4], p3 = packed[e + 6];
      float4 x0 = X4[(size_t)p0.x * 32 + c4];
      float4 x1 = X4[(size_t)p1.x * 32 + c4];
      float4 x2 = X4[(size_t)p2.x * 32 + c4];
      float4 x3 = X4[(size_t)p3.x * 32 + c4];
      float w0 = __int_as_float(p0.y), w1 = __int_as_float(p1.y);
      float w2 = __int_as_float(p2.y), w3 = __int_as_float(p3.y);
      a0.x += w0*fmaxf(x0.x,0.f); a0.y += w0*fmaxf(x0.y,0.f);
      a0.z += w0*fmaxf(x0.z,0.f); a0.w += w0*fmaxf(x0.w,0.f);
      a1.x += w1*fmaxf(x1.x,0.f); a1.y += w1*fmaxf(x1.y,0.f);
      a1.z += w1*fmaxf(x1.z,0.f); a1.w += w1*fmaxf(x1.w,0.f);
      a2.x += w2*fmaxf(x2.x,0.f); a2.y += w2*fmaxf(x2.y,0.f);
      a2.z += w2*fmaxf(x2.z,0.f); a2.w += w2*fmaxf(x2.w,0.f);
      a3.x += w3*fmaxf(x3.x,0.f); a3.y += w3*fmaxf(x3.y,0.f);
      a3.z += w3*fmaxf(x3.z,0.f); a3.w += w3*fmaxf(x3.w,0.f);
    }
    for (; e < end; e += 2) {
      int2 p = packed[e];
      float4 x = X4[(size_t)p.x * 32 + c4];
      float w = __int_as_float(p.y);
      a0.x += w*fmaxf(x.x,0.f); a0.y += w*fmaxf(x.y,0.f);
      a0.z += w*fmaxf(x.z,0.f); a0.w += w*fmaxf(x.w,0.f);
    }
    a0.x += a1.x + a2.x + a3.x; a0.y += a1.y + a2.y + a3.y;
    a0.z += a1.z + a2.z + a3.z; a0.w += a1.w + a2.w + a3.w;
    a0.x += __shfl_xor(a0.x, 32); a0.y += __shfl_xor(a0.y, 32);
    a0.z += __shfl_xor(a0.z, 32); a0.w += __shfl_xor(a0.w, 32);
  }
  if (half == 0 && tgt < NTGT)
    reinterpret_cast<float4*>(g)[(size_t)tgt * 32 + c4] = a0;
}

// ------- mini GEMM: (g @ W2) + b2 over 10120 target rows -> bf16-split T/Q --
__global__ __launch_bounds__(256)
void mini_gemm(const float* __restrict__ A, const unsigned short* __restrict__ WThi,
               const unsigned short* __restrict__ WTlo, const float* __restrict__ b2,
               unsigned short* __restrict__ Thi, unsigned short* __restrict__ Tlo,
               unsigned short* __restrict__ Qhi, unsigned short* __restrict__ Qlo) {
  const int tid = threadIdx.x;
  const int w = tid >> 6, lane = tid & 63;
  const int m0 = blockIdx.x * 64 + w * 16;
  int arow = m0 + (lane & 15); if (arow > NTGT - 1) arow = NTGT - 1;
  const int koff = (lane >> 4) * 8;

  f32x4 acc[8];
#pragma unroll
  for (int t = 0; t < 8; ++t) acc[t] = {0.f, 0.f, 0.f, 0.f};

#pragma unroll
  for (int ks = 0; ks < 4; ++ks) {
    const float* ap = &A[(size_t)arow * NHID + ks * 32 + koff];
    float4 a0 = *reinterpret_cast<const float4*>(ap);
    float4 a1 = *reinterpret_cast<const float4*>(ap + 4);
    short8v ah, al;
    split8(a0, a1, ah, al);
#pragma unroll
    for (int t = 0; t < 8; ++t) {
      size_t bo = (size_t)(t * 16 + (lane & 15)) * NHID + ks * 32 + koff;
      short8v bh = *reinterpret_cast<const short8v*>(&WThi[bo]);
      short8v bl = *reinterpret_cast<const short8v*>(&WTlo[bo]);
      acc[t] = __builtin_amdgcn_mfma_f32_16x16x32_bf16(ah, bh, acc[t], 0, 0, 0);
      acc[t] = __builtin_amdgcn_mfma_f32_16x16x32_bf16(ah, bl, acc[t], 0, 0, 0);
      acc[t] = __builtin_amdgcn_mfma_f32_16x16x32_bf16(al, bh, acc[t], 0, 0, 0);
    }
  }
  const int crow0 = m0 + (lane >> 4) * 4;
#pragma unroll
  for (int j = 0; j < 4; ++j) {
    int row = crow0 + j;
    if (row < NTGT) {
#pragma unroll
      for (int t = 0; t < 8; ++t) {
        int col = t * 16 + (lane & 15);
        float val = acc[t][j] + b2[col];
        unsigned short h, l;
        splitbf(val, h, l);
        if (row < NTPAD) {
          Thi[(size_t)row * 128 + col] = h;
          Tlo[(size_t)row * 128 + col] = l;
        } else {
          Qhi[(size_t)(row - NTPAD) * 128 + col] = h;
          Qlo[(size_t)(row - NTPAD) * 128 + col] = l;
        }
      }
    }
  }
}

// ---------------- MFMA score: 32 rows/block, T-panel read once --------------
__global__ __launch_bounds__(512)
void score_mfma(const unsigned short* __restrict__ Qhi, const unsigned short* __restrict__ Qlo,
                const unsigned short* __restrict__ Thi, const unsigned short* __restrict__ Tlo,
                int* __restrict__ ccnt, float* __restrict__ candv, int* __restrict__ candi) {
  __shared__ float s[2 * 16 * CB];     // 80 KB
  const int tid = threadIdx.x;
  const int w = tid >> 6, lane = tid & 63;   // w in 0..7
  const int r0 = (blockIdx.x >> 3) * RB;
  const int j0 = (blockIdx.x & 7) * CB;

  int arow0 = r0 + (lane & 15);      if (arow0 > NTEST - 1) arow0 = NTEST - 1;
  int arow1 = r0 + 16 + (lane & 15); if (arow1 > NTEST - 1) arow1 = NTEST - 1;
  const int koff = (lane >> 4) * 8;
  short8v ah0[4], al0[4], ah1[4], al1[4];
#pragma unroll
  for (int ks = 0; ks < 4; ++ks) {
    ah0[ks] = *reinterpret_cast<const short8v*>(&Qhi[(size_t)arow0 * 128 + ks * 32 + koff]);
    al0[ks] = *reinterpret_cast<const short8v*>(&Qlo[(size_t)arow0 * 128 + ks * 32 + koff]);
    ah1[ks] = *reinterpret_cast<const short8v*>(&Qhi[(size_t)arow1 * 128 + ks * 32 + koff]);
    al1[ks] = *reinterpret_cast<const short8v*>(&Qlo[(size_t)arow1 * 128 + ks * 32 + koff]);
  }

#pragma unroll
  for (int t = 0; t < 5; ++t) {
    int colbase = w * 80 + t * 16;
    int col = j0 + colbase + (lane & 15);            // < NTPAD always
    const unsigned short* bh = &Thi[(size_t)col * 128 + koff];
    const unsigned short* bl = &Tlo[(size_t)col * 128 + koff];
    f32x4 a0 = {0.f, 0.f, 0.f, 0.f};
    f32x4 a1 = {0.f, 0.f, 0.f, 0.f};
#pragma unroll
    for (int ks = 0; ks < 4; ++ks) {
      short8v bhv = *reinterpret_cast<const short8v*>(&bh[ks * 32]);
      short8v blv = *reinterpret_cast<const short8v*>(&bl[ks * 32]);
      a0 = __builtin_amdgcn_mfma_f32_16x16x32_bf16(ah0[ks], bhv, a0, 0, 0, 0);
      a1 = __builtin_amdgcn_mfma_f32_16x16x32_bf16(ah1[ks], bhv, a1, 0, 0, 0);
      a0 = __builtin_amdgcn_mfma_f32_16x16x32_bf16(ah0[ks], blv, a0, 0, 0, 0);
      a1 = __builtin_amdgcn_mfma_f32_16x16x32_bf16(ah1[ks], blv, a1, 0, 0, 0);
      a0 = __builtin_amdgcn_mfma_f32_16x16x32_bf16(al0[ks], bhv, a0, 0, 0, 0);
      a1 = __builtin_amdgcn_mfma_f32_16x16x32_bf16(al1[ks], bhv, a1, 0, 0, 0);
    }
    int sc = colbase + (lane & 15);
    int sr = (lane >> 4) * 4;
#pragma unroll
    for (int r = 0; r < 4; ++r) s[swz(sr + r, sc)] = a0[r];
#pragma unroll
    for (int r = 0; r < 4; ++r) s[16 * CB + swz(sr + r, sc)] = a1[r];
  }
  __syncthreads();

  const unsigned long long ltm = ((unsigned long long)1 << lane) - 1;

#pragma unroll
  for (int g = 0; g < 2; ++g) {
    const float* sg = s + g * 16 * CB;
#pragma unroll
    for (int r = 0; r < 2; ++r) {
      const int m = w * 2 + r;
      const int row = r0 + g * 16 + m;
      if (row >= NTEST) continue;
      float v[10];
#pragma unroll
      for (int k = 0; k < 10; ++k) {
        int c = lane + 64 * k;
        v[k] = (j0 + c < NTRAIN) ? sg[swz(m, c)] : -INFINITY;
      }
      float t0 = fmaxf(v[0], v[1]), t1 = fmaxf(v[2], v[3]);
      float t2 = fmaxf(v[4], v[5]), t3 = fmaxf(v[6], v[7]);
      float sv = fmaxf(fmaxf(fmaxf(t0, t1), fmaxf(t2, t3)), fmaxf(v[8], v[9]));
#pragma unroll
      for (int k = 2; k <= 64; k <<= 1) {
#pragma unroll
        for (int j = k >> 1; j > 0; j >>= 1) {
          float ov = __shfl_xor(sv, j);
          bool keepMax = ((lane & j) == 0) == ((lane & k) == 0 || k == 64);
          sv = keepMax ? fmaxf(sv, ov) : fminf(sv, ov);
        }
      }
      float T = __shfl(sv, 19);       // 20th-largest lane-max

      int myo[10];
      int tot = 0;
#pragma unroll
      for (int k = 0; k < 10; ++k) {
        unsigned long long mk = __ballot(v[k] >= T);
        myo[k] = tot + (int)__popcll(mk & ltm);
        tot += (int)__popcll(mk);
      }
      if (tot <= 64) {                // typical tot ~ 22
        int base = 0;
        if (lane == 0) base = atomicAdd(&ccnt[row], tot);
        base = __shfl(base, 0);
        float* cv = candv + (size_t)row * CCAP + base;
        int*   ci = candi + (size_t)row * CCAP + base;
#pragma unroll
        for (int k = 0; k < 10; ++k) {
          if (v[k] >= T) { cv[myo[k]] = v[k]; ci[myo[k]] = j0 + lane + 64 * k; }
        }
      } else {                        // rare dense path: exact top-20
        float selv = 0.f; int seli = 0;
#pragma unroll
        for (int it = 0; it < TOPK; ++it) {
          float bv = v[0]; int bk = 0;
#pragma unroll
          for (int k = 1; k < 10; ++k)
            if (v[k] > bv) { bv = v[k]; bk = k; }
          int bj = lane + 64 * bk;
#pragma unroll
          for (int off = 1; off < 64; off <<= 1) {
            float ov = __shfl_xor(bv, off);
            int   oj = __shfl_xor(bj, off);
            if (ov > bv || (ov == bv && oj < bj)) { bv = ov; bj = oj; }
          }
          if (lane == it) { selv = bv; seli = j0 + bj; }
          int ck = bj >> 6;
          if ((bj & 63) == lane) {
#pragma unroll
            for (int k = 0; k < 10; ++k)
              if (k == ck) v[k] = -INFINITY;
          }
        }
        int base = 0;
        if (lane == 0) base = atomicAdd(&ccnt[row], TOPK);
        base = __shfl(base, 0);
        if (lane < TOPK) {
          candv[(size_t)row * CCAP + base + lane] = selv;
          candi[(size_t)row * CCAP + base + lane] = seli;
        }
      }
    }
  }
}

// 64-lane bitonic sort, descending by (value, then ascending index)
__device__ inline void sort64_vi(float& v, int& idx, int lane) {
#pragma unroll
  for (int k = 2; k <= 64; k <<= 1) {
#pragma unroll
    for (int j = k >> 1; j > 0; j >>= 1) {
      float ov = __shfl_xor(v, j);
      int   oi = __shfl_xor(idx, j);
      bool first = (v > ov) || (v == ov && idx < oi);
      bool keepMine = (((lane & j) == 0) == ((lane & k) == 0 || k == 64)) ? first : !first;
      if (!keepMine) { v = ov; idx = oi; }
    }
  }
}

// ---------------- merge: streaming bitonic top-20 + softmax + preds ----------
__global__ __launch_bounds__(256)
void merge_topk(const float* __restrict__ candv, const int* __restrict__ candi,
                const int* __restrict__ ccnt, const float* __restrict__ lab,
                float* __restrict__ out) {
  const int tid = threadIdx.x;
  const int wv = tid >> 6, lane = tid & 63;
  const int row = blockIdx.x * 4 + wv;
  const size_t base = (size_t)row * CCAP;
  const int C = ccnt[row];

  float v = -INFINITY; int idx = INT_MAX;
  int take = C < 64 ? C : 64;
  if (lane < take) { v = candv[base + lane]; idx = candi[base + lane]; }
  sort64_vi(v, idx, lane);
  int consumed = take;
  while (consumed < C) {
    int n = C - consumed; if (n > 44) n = 44;
    if (lane >= TOPK) {
      int p = lane - TOPK;
      if (p < n) { v = candv[base + consumed + p]; idx = candi[base + consumed + p]; }
      else       { v = -INFINITY; idx = INT_MAX; }
    }
    sort64_vi(v, idx, lane);
    consumed += n;
  }
  float mx = __shfl(v, 0);
  float wgt = (lane < TOPK) ? expf(v - mx) : 0.f;
  float sum = wgt;
#pragma unroll
  for (int off = 1; off < 64; off <<= 1) sum += __shfl_xor(sum, off);

  float acc = 0.f;
#pragma unroll
  for (int i = 0; i < TOPK; ++i) {
    float wi = __shfl(wgt, i);
    int   ji = __shfl(idx, i);
    if (lane < NCLS) acc += wi * lab[(size_t)ji * NCLS + lane];
  }
  if (lane < NCLS) out[(size_t)row * NCLS + lane] = acc / sum;
}

extern "C" void kernel_launch(void* const* d_in, const int* in_sizes, int n_in,
                              void* d_out, int out_size, void* d_ws, size_t ws_size,
                              hipStream_t stream) {
  const float* feat   = (const float*)d_in[0];
  const float* ew     = (const float*)d_in[1];
  const float* onehot = (const float*)d_in[2];
  const float* W1     = (const float*)d_in[3];
  const float* b1     = (const float*)d_in[4];
  const float* W2     = (const float*)d_in[5];
  const float* b2     = (const float*)d_in[6];
  const int*   ei     = (const int*)d_in[7];
  const int*   itr    = (const int*)d_in[8];
  const int*   ite    = (const int*)d_in[9];
  float* out = (float*)d_out;
  float* ws  = (float*)d_ws;

  float* bufA   = ws;                                  // [NNODE][128] X1; later T/Q + g
  float* bufH   = bufA + (size_t)NNODE * NHID;         // [NNODE][128] h; later candidates
  int*   cursor = (int*)(bufH + (size_t)NNODE * NHID); // [NNODE]
  int2*  packed = (int2*)(cursor + ((NNODE + 15) & ~15)); // [NEDGE]
  unsigned short* WT1hi = (unsigned short*)(packed + NEDGE);    // [128][256]
  unsigned short* WT1lo = WT1hi + 128 * NFEAT;
  unsigned short* WT2hi = WT1lo + 128 * NFEAT;                  // [128][128]
  unsigned short* WT2lo = WT2hi + 128 * NHID;
  float* lab  = (float*)(WT2lo + 128 * NHID);                   // [5000][16]
  int*   ccnt = (int*)(lab + (size_t)NTRAIN * NCLS);            // [5000]
  // after gather_nodes X1 (bufA) is dead: T/Q (5.2MB) then g (5.2MB) live there
  unsigned short* Thi = (unsigned short*)bufA;                  // [NTPAD][128]
  unsigned short* Tlo = Thi + (size_t)NTPAD * NHID;
  unsigned short* Qhi = Tlo + (size_t)NTPAD * NHID;             // [NTEST][128]
  unsigned short* Qlo = Qhi + (size_t)NTEST * NHID;
  float* g    = (float*)(Qlo + (size_t)NTEST * NHID);           // [NTGT][128] fp32
  // candidates live in bufH (h dead after gather_targets2): 2 x 10.2 MB
  float* candv = bufH;                                          // [5000][512]
  int*   candi = (int*)(bufH + (size_t)NTEST * CCAP);

  const int* esrc = ei;
  const int* edst = ei + NEDGE;

  // cursor zero (async memset) + fused prep/hist + scan + [gemm1 || fill_csr]
  hipMemsetAsync(cursor, 0, NNODE * sizeof(int), stream);
  int ptot = NFEAT * 128 + NHID * 128 + NTRAIN * NCLS + NTEST + NEDGE;
  prep_hist<<<(ptot + 255) / 256, 256, 0, stream>>>(
      W1, WT1hi, WT1lo, W2, WT2hi, WT2lo, onehot, itr, lab, ccnt, edst, cursor);
  scan_cnt<<<1, 1024, 0, stream>>>(cursor);
  gemm1_fill<<<GB1 + FB1, 256, 0, stream>>>(
      feat, WT1hi, WT1lo, bufA, esrc, edst, ew, cursor, packed);

  // h = propagate(X1)+b1 (full); g = propagate_targets(relu(h)); T/Q = g@W2+b2
  gather_nodes<<<NNODE / 4, 256, 0, stream>>>(bufA, bufH, cursor, packed, b1);
  gather_targets2<<<(NTGT + 3) / 4, 256, 0, stream>>>(bufH, cursor, packed, itr, ite, g);
  mini_gemm<<<(NTGT + 63) / 64, 256, 0, stream>>>(
      g, WT2hi, WT2lo, b2, Thi, Tlo, Qhi, Qlo);

  // scoring (panel-per-XCD 1D grid, 32 rows/block)
  score_mfma<<<((NTEST + RB - 1) / RB) * NCT, 512, 0, stream>>>(
      Qhi, Qlo, Thi, Tlo, ccnt, candv, candi);
  merge_topk<<<NTEST / 4, 256, 0, stream>>>(candv, candi, ccnt, lab, out);
}